// Round 9
// baseline (90.377 us; speedup 1.0000x reference)
//
#include <hip/hip_runtime.h>
#include <math.h>

#define HORIZON 20
#define DT      0.1f
#define EPS     1e-4f
#define V_MAX   0.22f
#define W_MAX   2.8f

// K(v,w) quadrant table. Two exact symmetries (both verified on HW):
//  fold1: K(-v,-w) acts as K(v,w) with e1 -> -e1
//  fold2: K(-v,w) = U K(v,w) T, T=diag(1,1,-1), U=diag(1,-1)
//    => when v1<0: flip e2 and negate du1.
// Table: v,w in [0,4], NQ x NQ nodes, AoS 16 B/node (6 fp16 + pad).
#define NQ     57
#define NODES  (NQ * NQ)
#define QHI    4.0f
#define INV_H  ((float)(NQ - 1) / QHI)     // 14.0

typedef _Float16 h2 __attribute__((ext_vector_type(2)));

__device__ __forceinline__ float softplus_f(float x) {
    return fmaxf(x, 0.0f) + log1pf(expf(-fabsf(x)));
}

// Exact 20-step Riccati at (vref, wref) -> K (2x3) row-major.
__device__ __forceinline__ void riccati_K(
    float vref, float wref,
    const float* __restrict__ q_raw, const float* __restrict__ r_raw,
    const float* __restrict__ qf_raw, float K[6])
{
    const float q0  = softplus_f(q_raw[0])  + EPS;
    const float q1  = softplus_f(q_raw[1])  + EPS;
    const float q2  = softplus_f(q_raw[2])  + EPS;
    const float r0e = softplus_f(r_raw[0])  + EPS + EPS;   // R diag + eps*I2
    const float r1e = softplus_f(r_raw[1])  + EPS + EPS;
    const float qf0 = softplus_f(qf_raw[0]) + EPS;
    const float qf1 = softplus_f(qf_raw[1]) + EPS;
    const float qf2 = softplus_f(qf_raw[2]) + EPS;

    const float dt  = DT;
    const float dt2 = dt * dt;
    const float dtw = dt * wref;
    const float dtv = dt * vref;

    float p00 = qf0, p01 = 0.f, p02 = 0.f, p11 = qf1, p12 = 0.f, p22 = qf2;
    float k00 = 0.f, k01 = 0.f, k02 = 0.f, k10 = 0.f, k11 = 0.f, k12 = 0.f;

    #pragma unroll
    for (int t = 0; t < HORIZON; ++t) {
        const float t00 = p00 - dtw * p01;
        const float t01 = p01 - dtw * p11;
        const float t02 = p02 - dtw * p12;
        const float t10 = dtw * p00 + p01;
        const float t11 = dtw * p01 + p11;
        const float t12 = dtw * p02 + p12;
        const float t20 = dtv * p01 + p02;
        const float t21 = dtv * p11 + p12;
        const float t22 = dtv * p12 + p22;

        const float s00 = r0e + dt2 * p00;
        const float s01 =       dt2 * p02;
        const float s11 = r1e + dt2 * p22;
        const float c = -dt * __builtin_amdgcn_rcpf(s00 * s11 - s01 * s01);
        const float cs11 = c * s11, cs01 = c * s01, cs00 = c * s00;

        k00 = cs11 * t00 - cs01 * t02;
        k01 = cs11 * t10 - cs01 * t12;
        k02 = cs11 * t20 - cs01 * t22;
        k10 = cs00 * t02 - cs01 * t00;
        k11 = cs00 * t12 - cs01 * t10;
        k12 = cs00 * t22 - cs01 * t20;

        const float a00 = 1.0f + dt * k00;
        const float a01 = dtw  + dt * k01;
        const float a02 =        dt * k02;
        const float a20 =        dt * k10;
        const float a21 =        dt * k11;
        const float a22 = 1.0f + dt * k12;

        p00 = q0 + t00 * a00 - t01 * dtw + t02 * a20;
        p01 =      t00 * a01 + t01       + t02 * a21;
        p02 =      t00 * a02 + t01 * dtv + t02 * a22;
        p11 = q1 + t10 * a01 + t11       + t12 * a21;
        p12 =      t10 * a02 + t11 * dtv + t12 * a22;
        p22 = q2 + t20 * a02 + t21 * dtv + t22 * a22;
    }
    K[0] = k00; K[1] = k01; K[2] = k02;
    K[3] = k10; K[4] = k11; K[5] = k12;
}

__device__ __forceinline__ unsigned pack2(float a, float b) {
    h2 h; h[0] = (_Float16)a; h[1] = (_Float16)b;
    return __builtin_bit_cast(unsigned, h);
}

// Build quadrant table (AoS uint4 nodes) at ws[0..NODES).
__global__ __launch_bounds__(256) void table_kernel(
    const float* __restrict__ q_raw, const float* __restrict__ r_raw,
    const float* __restrict__ qf_raw, uint4* __restrict__ tbl)
{
    const int idx = blockIdx.x * blockDim.x + threadIdx.x;
    if (idx >= NODES) return;
    const int iv = idx % NQ;
    const int iw = idx / NQ;
    const float v = (QHI / (float)(NQ - 1)) * (float)iv;
    const float w = (QHI / (float)(NQ - 1)) * (float)iw;
    float K[6];
    riccati_K(v, w, q_raw, r_raw, qf_raw, K);
    tbl[idx] = make_uint4(pack2(K[0], K[1]), pack2(K[2], K[3]),
                          pack2(K[4], K[5]), 0u);
}

// Double-folded bilinear gather: 4x ds_read_b128 + pk_fma_f16 interp.
__device__ __forceinline__ float2 eval_one(
    const uint4* __restrict__ nodes,
    float e0, float e1, float e2, float vref, float wref, bool* oor)
{
    const float s1 = (wref < 0.0f) ? -1.0f : 1.0f;   // fold1
    const float v1 = s1 * vref, w1 = s1 * wref;
    const float e1f = s1 * e1;
    const float s2 = (v1 < 0.0f) ? -1.0f : 1.0f;     // fold2
    const float vq = s2 * v1;
    const float e2f = s2 * e2;

    *oor = (vq > QHI) | (w1 > QHI);

    float fv = fminf(vq * INV_H, (float)(NQ - 1) - 1e-3f);
    float fw = fminf(w1 * INV_H, (float)(NQ - 1) - 1e-3f);
    const int iv = (int)fv;  const float av = fv - (float)iv;
    const int iw = (int)fw;  const float aw = fw - (float)iw;
    const int b = iw * NQ + iv;

    const uint4 A = nodes[b],      B = nodes[b + 1];
    const uint4 C = nodes[b + NQ], D = nodes[b + NQ + 1];

    const _Float16 hu00 = (_Float16)((1.0f - av) * (1.0f - aw));
    const _Float16 hu01 = (_Float16)(av * (1.0f - aw));
    const _Float16 hu10 = (_Float16)((1.0f - av) * aw);
    const _Float16 hu11 = (_Float16)(av * aw);
    const h2 W00 = {hu00, hu00}, W01 = {hu01, hu01},
             W10 = {hu10, hu10}, W11 = {hu11, hu11};

    #define H2(u) __builtin_bit_cast(h2, u)
    h2 r0 = W00 * H2(A.x) + W01 * H2(B.x) + W10 * H2(C.x) + W11 * H2(D.x);
    h2 r1 = W00 * H2(A.y) + W01 * H2(B.y) + W10 * H2(C.y) + W11 * H2(D.y);
    h2 r2 = W00 * H2(A.z) + W01 * H2(B.z) + W10 * H2(C.z) + W11 * H2(D.z);
    #undef H2

    const float k0 = (float)r0[0], k1 = (float)r0[1];
    const float k2 = (float)r1[0], k3 = (float)r1[1];
    const float k4 = (float)r2[0], k5 = (float)r2[1];

    const float du0 =       k0 * e0 + k1 * e1f + k2 * e2f;
    const float du1 = s2 * (k3 * e0 + k4 * e1f + k5 * e2f);
    const float v = fminf(fmaxf(vref - du0, -V_MAX), V_MAX);
    const float w = fminf(fmaxf(wref - du1, -W_MAX), W_MAX);
    return make_float2(v, w);
}

// 4 elements/thread. Hot path: pure gather. Cold path (execz-skipped, ~3% of
// waves): exact Riccati overwrite for out-of-quadrant elements.
__global__ __launch_bounds__(512, 4) void lqr_main(
    const float* __restrict__ ref,      // (B,5)
    const uint4* __restrict__ gt,       // global table (d_ws)
    const float* __restrict__ q_raw, const float* __restrict__ r_raw,
    const float* __restrict__ qf_raw,
    float* __restrict__ out,            // (B,2)
    int batch)
{
    __shared__ uint4 lds[NODES];                     // 51,984 B -> 3 blocks/CU LDS-wise
    for (int j = threadIdx.x; j < NODES; j += 512)
        lds[j] = gt[j];

    const int t    = blockIdx.x * 512 + threadIdx.x;
    const int base = 4 * t;

    if (base + 3 < batch) {
        // Issue ref loads before the barrier: HBM latency overlaps staging wait.
        const float4* r4 = reinterpret_cast<const float4*>(ref + 5 * base);
        const float4 d0 = r4[0], d1 = r4[1], d2 = r4[2], d3 = r4[3], d4 = r4[4];
        __syncthreads();

        const float r[20] = {d0.x,d0.y,d0.z,d0.w, d1.x,d1.y,d1.z,d1.w,
                             d2.x,d2.y,d2.z,d2.w, d3.x,d3.y,d3.z,d3.w,
                             d4.x,d4.y,d4.z,d4.w};
        bool o0, o1, o2, o3;
        const float2 c0 = eval_one(lds, r[0], r[1], r[2], r[3], r[4], &o0);
        const float2 c1 = eval_one(lds, r[5], r[6], r[7], r[8], r[9], &o1);
        const float2 c2 = eval_one(lds, r[10],r[11],r[12],r[13],r[14], &o2);
        const float2 c3 = eval_one(lds, r[15],r[16],r[17],r[18],r[19], &o3);

        float4* o4 = reinterpret_cast<float4*>(out + 2 * base);
        o4[0] = make_float4(c0.x, c0.y, c1.x, c1.y);
        o4[1] = make_float4(c2.x, c2.y, c3.x, c3.y);

        // Cold exact-overwrite path; reloads its 5 floats (no dynamic reg index).
        if (o0 | o1 | o2 | o3) {
            const bool oo[4] = {o0, o1, o2, o3};
            #pragma unroll
            for (int k = 0; k < 4; ++k) {
                if (oo[k]) {
                    const float* rp = ref + 5 * (base + k);
                    const float e0 = rp[0], e1 = rp[1], e2 = rp[2];
                    const float vr = rp[3], wr = rp[4];
                    float K[6];
                    riccati_K(vr, wr, q_raw, r_raw, qf_raw, K);
                    const float du0 = K[0]*e0 + K[1]*e1 + K[2]*e2;
                    const float du1 = K[3]*e0 + K[4]*e1 + K[5]*e2;
                    out[2*(base+k)]   = fminf(fmaxf(vr - du0, -V_MAX), V_MAX);
                    out[2*(base+k)+1] = fminf(fmaxf(wr - du1, -W_MAX), W_MAX);
                }
            }
        }
    } else {
        __syncthreads();
        for (int k = 0; k < 4; ++k) {
            const int idx = base + k;
            if (idx >= batch) break;
            const float* rp = ref + 5 * idx;
            bool oo;
            const float2 c = eval_one(lds, rp[0], rp[1], rp[2], rp[3], rp[4], &oo);
            float vv = c.x, ww = c.y;
            if (oo) {
                float K[6];
                riccati_K(rp[3], rp[4], q_raw, r_raw, qf_raw, K);
                const float du0 = K[0]*rp[0] + K[1]*rp[1] + K[2]*rp[2];
                const float du1 = K[3]*rp[0] + K[4]*rp[1] + K[5]*rp[2];
                vv = fminf(fmaxf(rp[3] - du0, -V_MAX), V_MAX);
                ww = fminf(fmaxf(rp[4] - du1, -W_MAX), W_MAX);
            }
            out[2*idx]   = vv;
            out[2*idx+1] = ww;
        }
    }
}

extern "C" void kernel_launch(void* const* d_in, const int* in_sizes, int n_in,
                              void* d_out, int out_size, void* d_ws, size_t ws_size,
                              hipStream_t stream) {
    const float* ref    = (const float*)d_in[0];
    const float* q_raw  = (const float*)d_in[1];
    const float* r_raw  = (const float*)d_in[2];
    const float* qf_raw = (const float*)d_in[3];
    float* out = (float*)d_out;
    uint4* tbl = (uint4*)d_ws;                 // NODES*16 B ~= 52 KB

    const int batch = in_sizes[0] / 5;
    const int quads = (batch + 3) / 4;

    table_kernel<<<(NODES + 255) / 256, 256, 0, stream>>>(q_raw, r_raw, qf_raw, tbl);

    const int grid = (quads + 511) / 512;
    lqr_main<<<grid, 512, 0, stream>>>(ref, tbl, q_raw, r_raw, qf_raw, out, batch);
}

// Round 10
// 88.224 us; speedup vs baseline: 1.0244x; 1.0244x over previous
//
#include <hip/hip_runtime.h>
#include <math.h>

#define HORIZON 20
#define DT      0.1f
#define EPS     1e-4f
#define V_MAX   0.22f
#define W_MAX   2.8f

// K(v,w) quadrant table. Two exact symmetries (both verified on HW):
//  fold1: K(-v,-w) acts as K(v,w) with e1 -> -e1
//  fold2: K(-v,w) = U K(v,w) T, T=diag(1,1,-1), U=diag(1,-1)
//    => when v1<0: flip e2 and negate du1.
// Table: v,w in [0,4], NQ x NQ nodes, AoS 16 B/node (6 fp16 + pad).
#define NQ     57
#define NODES  (NQ * NQ)
#define QHI    4.0f
#define INV_H  ((float)(NQ - 1) / QHI)     // 14.0

// d_ws layout (dwords): [0] oor count; [64, 64+CAP) oor index list;
// [262144, ...) table (NODES uint4).
#define CAP      65536
#define LIST_OFF 64
#define TBL_OFF  262144

typedef _Float16 h2 __attribute__((ext_vector_type(2)));

__device__ __forceinline__ float softplus_f(float x) {
    return fmaxf(x, 0.0f) + log1pf(expf(-fabsf(x)));
}

// Exact 20-step Riccati at (vref, wref) -> K (2x3) row-major.
__device__ void riccati_K(
    float vref, float wref,
    const float* __restrict__ q_raw, const float* __restrict__ r_raw,
    const float* __restrict__ qf_raw, float K[6])
{
    const float q0  = softplus_f(q_raw[0])  + EPS;
    const float q1  = softplus_f(q_raw[1])  + EPS;
    const float q2  = softplus_f(q_raw[2])  + EPS;
    const float r0e = softplus_f(r_raw[0])  + EPS + EPS;   // R diag + eps*I2
    const float r1e = softplus_f(r_raw[1])  + EPS + EPS;
    const float qf0 = softplus_f(qf_raw[0]) + EPS;
    const float qf1 = softplus_f(qf_raw[1]) + EPS;
    const float qf2 = softplus_f(qf_raw[2]) + EPS;

    const float dt  = DT;
    const float dt2 = dt * dt;
    const float dtw = dt * wref;
    const float dtv = dt * vref;

    float p00 = qf0, p01 = 0.f, p02 = 0.f, p11 = qf1, p12 = 0.f, p22 = qf2;
    float k00 = 0.f, k01 = 0.f, k02 = 0.f, k10 = 0.f, k11 = 0.f, k12 = 0.f;

    #pragma unroll
    for (int t = 0; t < HORIZON; ++t) {
        const float t00 = p00 - dtw * p01;
        const float t01 = p01 - dtw * p11;
        const float t02 = p02 - dtw * p12;
        const float t10 = dtw * p00 + p01;
        const float t11 = dtw * p01 + p11;
        const float t12 = dtw * p02 + p12;
        const float t20 = dtv * p01 + p02;
        const float t21 = dtv * p11 + p12;
        const float t22 = dtv * p12 + p22;

        const float s00 = r0e + dt2 * p00;
        const float s01 =       dt2 * p02;
        const float s11 = r1e + dt2 * p22;
        const float c = -dt * __builtin_amdgcn_rcpf(s00 * s11 - s01 * s01);
        const float cs11 = c * s11, cs01 = c * s01, cs00 = c * s00;

        k00 = cs11 * t00 - cs01 * t02;
        k01 = cs11 * t10 - cs01 * t12;
        k02 = cs11 * t20 - cs01 * t22;
        k10 = cs00 * t02 - cs01 * t00;
        k11 = cs00 * t12 - cs01 * t10;
        k12 = cs00 * t22 - cs01 * t20;

        const float a00 = 1.0f + dt * k00;
        const float a01 = dtw  + dt * k01;
        const float a02 =        dt * k02;
        const float a20 =        dt * k10;
        const float a21 =        dt * k11;
        const float a22 = 1.0f + dt * k12;

        p00 = q0 + t00 * a00 - t01 * dtw + t02 * a20;
        p01 =      t00 * a01 + t01       + t02 * a21;
        p02 =      t00 * a02 + t01 * dtv + t02 * a22;
        p11 = q1 + t10 * a01 + t11       + t12 * a21;
        p12 =      t10 * a02 + t11 * dtv + t12 * a22;
        p22 = q2 + t20 * a02 + t21 * dtv + t22 * a22;
    }
    K[0] = k00; K[1] = k01; K[2] = k02;
    K[3] = k10; K[4] = k11; K[5] = k12;
}

__device__ __forceinline__ unsigned pack2(float a, float b) {
    h2 h; h[0] = (_Float16)a; h[1] = (_Float16)b;
    return __builtin_bit_cast(unsigned, h);
}

// Build quadrant table (AoS uint4 nodes) + zero the oor counter.
__global__ __launch_bounds__(256) void table_kernel(
    const float* __restrict__ q_raw, const float* __restrict__ r_raw,
    const float* __restrict__ qf_raw, unsigned* __restrict__ ws)
{
    const int idx = blockIdx.x * blockDim.x + threadIdx.x;
    if (idx == 0) ws[0] = 0u;
    if (idx >= NODES) return;
    const int iv = idx % NQ;
    const int iw = idx / NQ;
    const float v = (QHI / (float)(NQ - 1)) * (float)iv;
    const float w = (QHI / (float)(NQ - 1)) * (float)iw;
    float K[6];
    riccati_K(v, w, q_raw, r_raw, qf_raw, K);
    uint4* tbl = reinterpret_cast<uint4*>(ws + TBL_OFF);
    tbl[idx] = make_uint4(pack2(K[0], K[1]), pack2(K[2], K[3]),
                          pack2(K[4], K[5]), 0u);
}

// Double-folded bilinear gather: 4x ds_read_b128 + pk_fma_f16 interp.
__device__ __forceinline__ float2 eval_one(
    const uint4* __restrict__ nodes,
    float e0, float e1, float e2, float vref, float wref, bool* oor)
{
    const float s1 = (wref < 0.0f) ? -1.0f : 1.0f;   // fold1
    const float v1 = s1 * vref, w1 = s1 * wref;
    const float e1f = s1 * e1;
    const float s2 = (v1 < 0.0f) ? -1.0f : 1.0f;     // fold2
    const float vq = s2 * v1;
    const float e2f = s2 * e2;

    *oor = (vq > QHI) | (w1 > QHI);

    float fv = fminf(vq * INV_H, (float)(NQ - 1) - 1e-3f);
    float fw = fminf(w1 * INV_H, (float)(NQ - 1) - 1e-3f);
    const int iv = (int)fv;  const float av = fv - (float)iv;
    const int iw = (int)fw;  const float aw = fw - (float)iw;
    const int b = iw * NQ + iv;

    const uint4 A = nodes[b],      B = nodes[b + 1];
    const uint4 C = nodes[b + NQ], D = nodes[b + NQ + 1];

    const _Float16 hu00 = (_Float16)((1.0f - av) * (1.0f - aw));
    const _Float16 hu01 = (_Float16)(av * (1.0f - aw));
    const _Float16 hu10 = (_Float16)((1.0f - av) * aw);
    const _Float16 hu11 = (_Float16)(av * aw);
    const h2 W00 = {hu00, hu00}, W01 = {hu01, hu01},
             W10 = {hu10, hu10}, W11 = {hu11, hu11};

    #define H2(u) __builtin_bit_cast(h2, u)
    h2 r0 = W00 * H2(A.x) + W01 * H2(B.x) + W10 * H2(C.x) + W11 * H2(D.x);
    h2 r1 = W00 * H2(A.y) + W01 * H2(B.y) + W10 * H2(C.y) + W11 * H2(D.y);
    h2 r2 = W00 * H2(A.z) + W01 * H2(B.z) + W10 * H2(C.z) + W11 * H2(D.z);
    #undef H2

    const float k0 = (float)r0[0], k1 = (float)r0[1];
    const float k2 = (float)r1[0], k3 = (float)r1[1];
    const float k4 = (float)r2[0], k5 = (float)r2[1];

    const float du0 =       k0 * e0 + k1 * e1f + k2 * e2f;
    const float du1 = s2 * (k3 * e0 + k4 * e1f + k5 * e2f);
    const float v = fminf(fmaxf(vref - du0, -V_MAX), V_MAX);
    const float w = fminf(fmaxf(wref - du1, -W_MAX), W_MAX);
    return make_float2(v, w);
}

// 4 elements/thread; ref loads issued before the staging barrier; hot path
// contains NO Riccati (keeps VGPR low, no spills) — oor elems go to a list.
__global__ __launch_bounds__(512, 4) void lqr_main(
    const float* __restrict__ ref,      // (B,5)
    unsigned* __restrict__ ws,          // count / list / table
    float* __restrict__ out,            // (B,2)
    int batch)
{
    __shared__ uint4 lds[NODES];                     // 51,984 B
    const uint4* gt = reinterpret_cast<const uint4*>(ws + TBL_OFF);
    for (int j = threadIdx.x; j < NODES; j += 512)
        lds[j] = gt[j];

    const int t    = blockIdx.x * 512 + threadIdx.x;
    const int base = 4 * t;

    unsigned* cnt  = ws;
    unsigned* list = ws + LIST_OFF;

    if (base + 3 < batch) {
        // HBM latency overlaps the staging barrier.
        const float4* r4 = reinterpret_cast<const float4*>(ref + 5 * base);
        const float4 d0 = r4[0], d1 = r4[1], d2 = r4[2], d3 = r4[3], d4 = r4[4];
        __syncthreads();

        const float r[20] = {d0.x,d0.y,d0.z,d0.w, d1.x,d1.y,d1.z,d1.w,
                             d2.x,d2.y,d2.z,d2.w, d3.x,d3.y,d3.z,d3.w,
                             d4.x,d4.y,d4.z,d4.w};
        bool o0, o1, o2, o3;
        const float2 c0 = eval_one(lds, r[0], r[1], r[2], r[3], r[4], &o0);
        const float2 c1 = eval_one(lds, r[5], r[6], r[7], r[8], r[9], &o1);
        const float2 c2 = eval_one(lds, r[10],r[11],r[12],r[13],r[14], &o2);
        const float2 c3 = eval_one(lds, r[15],r[16],r[17],r[18],r[19], &o3);

        float4* o4 = reinterpret_cast<float4*>(out + 2 * base);
        o4[0] = make_float4(c0.x, c0.y, c1.x, c1.y);
        o4[1] = make_float4(c2.x, c2.y, c3.x, c3.y);

        // Single cold branch (~3% of waves enter; inner ifs nest inside it).
        if (__builtin_expect(o0 | o1 | o2 | o3, 0)) {
            if (o0) { unsigned p = atomicAdd(cnt, 1u); if (p < CAP) list[p] = base;     }
            if (o1) { unsigned p = atomicAdd(cnt, 1u); if (p < CAP) list[p] = base + 1; }
            if (o2) { unsigned p = atomicAdd(cnt, 1u); if (p < CAP) list[p] = base + 2; }
            if (o3) { unsigned p = atomicAdd(cnt, 1u); if (p < CAP) list[p] = base + 3; }
        }
    } else {
        __syncthreads();
        for (int k = 0; k < 4; ++k) {
            const int idx = base + k;
            if (idx >= batch) break;
            const float* rp = ref + 5 * idx;
            bool oo;
            const float2 c = eval_one(lds, rp[0], rp[1], rp[2], rp[3], rp[4], &oo);
            out[2 * idx]     = c.x;
            out[2 * idx + 1] = c.y;
            if (oo) { unsigned p = atomicAdd(cnt, 1u); if (p < CAP) list[p] = idx; }
        }
    }
}

// Exact Riccati for rare out-of-quadrant elements (expected ~100-200).
__global__ __launch_bounds__(256) void fixup_kernel(
    const float* __restrict__ ref,
    const unsigned* __restrict__ ws,
    const float* __restrict__ q_raw, const float* __restrict__ r_raw,
    const float* __restrict__ qf_raw,
    float* __restrict__ out)
{
    const unsigned n = min(ws[0], (unsigned)CAP);
    const unsigned* list = ws + LIST_OFF;
    for (unsigned j = threadIdx.x; j < n; j += 256) {
        const unsigned idx = list[j];
        const float e0 = ref[5*idx], e1 = ref[5*idx+1], e2 = ref[5*idx+2];
        const float vr = ref[5*idx+3], wr = ref[5*idx+4];
        float K[6];
        riccati_K(vr, wr, q_raw, r_raw, qf_raw, K);
        const float du0 = K[0]*e0 + K[1]*e1 + K[2]*e2;
        const float du1 = K[3]*e0 + K[4]*e1 + K[5]*e2;
        out[2*idx]   = fminf(fmaxf(vr - du0, -V_MAX), V_MAX);
        out[2*idx+1] = fminf(fmaxf(wr - du1, -W_MAX), W_MAX);
    }
}

extern "C" void kernel_launch(void* const* d_in, const int* in_sizes, int n_in,
                              void* d_out, int out_size, void* d_ws, size_t ws_size,
                              hipStream_t stream) {
    const float* ref    = (const float*)d_in[0];
    const float* q_raw  = (const float*)d_in[1];
    const float* r_raw  = (const float*)d_in[2];
    const float* qf_raw = (const float*)d_in[3];
    float* out = (float*)d_out;
    unsigned* ws = (unsigned*)d_ws;

    const int batch = in_sizes[0] / 5;
    const int quads = (batch + 3) / 4;

    table_kernel<<<(NODES + 255) / 256, 256, 0, stream>>>(q_raw, r_raw, qf_raw, ws);

    const int grid = (quads + 511) / 512;
    lqr_main<<<grid, 512, 0, stream>>>(ref, ws, out, batch);

    fixup_kernel<<<1, 256, 0, stream>>>(ref, ws, q_raw, r_raw, qf_raw, out);
}